// Round 4
// baseline (470.894 us; speedup 1.0000x reference)
//
#include <hip/hip_runtime.h>

// SuperLoRAGroup: out = FWHT24( G * Pi( FWHT24( pad( sign * vec(Bw@A)/16 ) ) ) )
// FWHT1 output periodic with period 2^22 => gather table W = 16MB only.
//
// P1 : GEMM+sign fused, FWHT bits 0..13 per 16K chunk            -> ws (16MB)
// P2 : FWHT bits 14..21 (256-pt, stride 2^14), in-place on ws    (k_fwht_mid)
// P3 : z[j] = ws[perm[j]&m]*G[j]*2^-24, FWHT bits 0..13          -> d_out
//      UNPHASED gathers: k3 is address-rate-bound (~4 addr/cyc/CU TA floor
//      = ~109us for 16M lane-addresses); 3 pacing variants (4ph/drain,
//      4ph/vmcnt8, 8ph/vmcnt4) all measured 134-137us with +-12% FETCH swing
//      => L2 slice residency is irrelevant, barriers are pure overhead.
//      All 16 gathers issue unguarded for max MLP; G*2^-24 pre-staged in LDS
//      keeps VGPRs <= 64 (2 blocks/CU at 64KB LDS).
// P4 : FWHT bits 14..23 fused in ONE pass: bits 22..23 radix-4 in REGISTERS,
//      then bits 14..21 per segment through a 32KB LDS tile (256x32 floats).
//      All global accesses are full 128B lines per row.

#define THREADS 1024
#define K4_THREADS 512

typedef float vf4 __attribute__((ext_vector_type(4)));
typedef int vi4 __attribute__((ext_vector_type(4)));

constexpr float kScaling = 0.0625f;             // alpha/rank = 1/16
constexpr float kNorm = 5.9604644775390625e-8f; // 2^-24 (both fwht norms)

__device__ __forceinline__ void fwht16(float r[16]) {
#pragma unroll
  for (int s = 1; s < 16; s <<= 1) {
#pragma unroll
    for (int i = 0; i < 16; i++) {
      if (!(i & s)) {
        float a = r[i];
        float b = r[i | s];
        r[i] = a + b;
        r[i | s] = a - b;
      }
    }
  }
}

// FWHT over the 14 low bits of a 16384-float LDS tile (radix 16/16/16/4).
// Final round streams results straight to dst4. Caller syncs after fill.
template <bool NT>
__device__ __forceinline__ void fwht_lo_rounds(float* lds, int t, vf4* dst4) {
  vf4* lds4 = (vf4*)lds;
  // bits 0..3: 16 contiguous floats per thread
  {
    float r[16];
#pragma unroll
    for (int q = 0; q < 4; q++) {
      vf4 v = lds4[t * 4 + q];
#pragma unroll
      for (int c = 0; c < 4; c++) r[4 * q + c] = v[c];
    }
    fwht16(r);
#pragma unroll
    for (int q = 0; q < 4; q++) {
      vf4 v;
#pragma unroll
      for (int c = 0; c < 4; c++) v[c] = r[4 * q + c];
      lds4[t * 4 + q] = v;
    }
  }
  __syncthreads();
  // bits 4..7 (b32 stride 16)
  {
    const int c = (t & 15) | ((t >> 4) << 8);
    float r[16];
#pragma unroll
    for (int k = 0; k < 16; k++) r[k] = lds[c + (k << 4)];
    fwht16(r);
#pragma unroll
    for (int k = 0; k < 16; k++) lds[c + (k << 4)] = r[k];
  }
  __syncthreads();
  // bits 8..11 (b32 stride 256)
  {
    const int c = (t & 255) | ((t >> 8) << 12);
    float r[16];
#pragma unroll
    for (int k = 0; k < 16; k++) r[k] = lds[c + (k << 8)];
    fwht16(r);
#pragma unroll
    for (int k = 0; k < 16; k++) lds[c + (k << 8)] = r[k];
  }
  __syncthreads();
  // bits 12..13 (radix-4 on float4 payload) fused with global store
  {
    vf4 v0 = lds4[t + 0 * 1024];
    vf4 v1 = lds4[t + 1 * 1024];
    vf4 v2 = lds4[t + 2 * 1024];
    vf4 v3 = lds4[t + 3 * 1024];
    vf4 e0 = v0 + v1, e1 = v0 - v1;
    vf4 e2 = v2 + v3, e3 = v2 - v3;
    vf4 o0 = e0 + e2, o1 = e1 + e3, o2 = e0 - e2, o3 = e1 - e3;
    if (NT) {
      __builtin_nontemporal_store(o0, &dst4[t + 0 * 1024]);
      __builtin_nontemporal_store(o1, &dst4[t + 1 * 1024]);
      __builtin_nontemporal_store(o2, &dst4[t + 2 * 1024]);
      __builtin_nontemporal_store(o3, &dst4[t + 3 * 1024]);
    } else {
      dst4[t + 0 * 1024] = o0;
      dst4[t + 1 * 1024] = o1;
      dst4[t + 2 * 1024] = o2;
      dst4[t + 3 * 1024] = o3;
    }
  }
}

// P1: delta=(Bw@A)/16, *sign, FWHT bits0..13 -> W. 256 blocks.
__global__ __launch_bounds__(THREADS) void k1_build_fwht_lo(
    const float* __restrict__ A, const float* __restrict__ Bw,
    const float* __restrict__ sgn, float* __restrict__ W) {
  __shared__ float lds[16384];
  const int t = threadIdx.x;
  const int blk = blockIdx.x;
  const unsigned base = (unsigned)blk << 14;

  float a0[16], a1[16];
#pragma unroll
  for (int k = 0; k < 16; k++) {
    a0[k] = A[k * 2048 + t];
    a1[k] = A[k * 2048 + t + 1024];
  }
  const int r0 = blk * 8;
#pragma unroll
  for (int rl = 0; rl < 8; rl++) {
    float s0 = 0.f, s1 = 0.f;
#pragma unroll
    for (int k = 0; k < 16; k++) {
      float b = Bw[(r0 + rl) * 16 + k];
      s0 += b * a0[k];
      s1 += b * a1[k];
    }
    const int l0 = rl * 2048 + t;
    const int l1 = l0 + 1024;
    lds[l0] = s0 * kScaling * sgn[base + l0];
    lds[l1] = s1 * kScaling * sgn[base + l1];
  }
  __syncthreads();
  fwht_lo_rounds<false>(lds, t, (vf4*)W + ((unsigned)blk << 12));
}

// 256-pt FWHT over bits 14..21 within a 2^22-float segment, in-place.
// Grid = n_segments*256; seg = blockIdx>>8, col-tile = blockIdx&255.
// (Used for the W workspace only.)
__global__ __launch_bounds__(THREADS) void k_fwht_mid(float* __restrict__ buf) {
  __shared__ float lds[16384];
  vf4* lds4 = (vf4*)lds;
  const int t = threadIdx.x;
  const int seg = blockIdx.x >> 8;
  const int c0 = (blockIdx.x & 255) * 16; // float4-column base
  vf4* B4 = (vf4*)buf + ((unsigned)seg << 20); // 256 rows x 4096 f4-cols
#pragma unroll
  for (int m = 0; m < 4; m++) {
    const int idx4 = t + THREADS * m;
    const int row = idx4 >> 4, c4 = idx4 & 15;
    lds4[idx4] = B4[row * 4096 + c0 + c4]; // 256B/row segments
  }
  __syncthreads();
  const int c4 = t & 15;
  const int f = t >> 4; // 0..63
#pragma unroll
  for (int r = 0; r < 4; r++) {
    const int m = 1 << (2 * r);
    int rows[4];
#pragma unroll
    for (int k2 = 0; k2 < 4; k2++)
      rows[k2] = (f & (m - 1)) + k2 * m + (f >> (2 * r)) * (m << 2);
    vf4 v0 = lds4[rows[0] * 16 + c4];
    vf4 v1 = lds4[rows[1] * 16 + c4];
    vf4 v2 = lds4[rows[2] * 16 + c4];
    vf4 v3 = lds4[rows[3] * 16 + c4];
    vf4 e0 = v0 + v1, e1 = v0 - v1;
    vf4 e2 = v2 + v3, e3 = v2 - v3;
    vf4 o0 = e0 + e2, o1 = e1 + e3, o2 = e0 - e2, o3 = e1 - e3;
    if (r < 3) {
      lds4[rows[0] * 16 + c4] = o0;
      lds4[rows[1] * 16 + c4] = o1;
      lds4[rows[2] * 16 + c4] = o2;
      lds4[rows[3] * 16 + c4] = o3;
      __syncthreads();
    } else {
      B4[rows[0] * 4096 + c0 + c4] = o0;
      B4[rows[1] * 4096 + c0 + c4] = o1;
      B4[rows[2] * 4096 + c0 + c4] = o2;
      B4[rows[3] * 4096 + c0 + c4] = o3;
    }
  }
}

// P3: z = W[perm&mask]*G*2^-24, FWHT bits0..13 -> out. 1024 blocks.
// Unphased: all 16 gathers issue unguarded, 16 outstanding per thread.
// k3 is TA address-rate-bound; no barriers/pacing (see header comment).
// G*2^-24 staged in this thread's own LDS slots immediately (frees 16 VGPRs;
// same-thread LDS RAW needs no barrier).
__global__ __launch_bounds__(THREADS, 8) void k3_perm_fwht_lo(
    const float* __restrict__ W, const int* __restrict__ perm,
    const float* __restrict__ G, float* __restrict__ out) {
  __shared__ float lds[16384];
  vf4* lds4 = (vf4*)lds;
  const int t = threadIdx.x;
  const unsigned base4 = (unsigned)blockIdx.x << 12;
  const vi4* P4 = (const vi4*)perm + base4;
  const vf4* G4 = (const vf4*)G + base4;
  int src[16];
#pragma unroll
  for (int m = 0; m < 4; m++) {
    const int idx4 = t + THREADS * m;
    vi4 p = __builtin_nontemporal_load(&P4[idx4]);
    vf4 g = __builtin_nontemporal_load(&G4[idx4]);
#pragma unroll
    for (int c = 0; c < 4; c++) src[4 * m + c] = p[c] & 0x3FFFFF;
    lds4[idx4] = g * kNorm; // own slot; no cross-thread use until final sync
  }
  float wv[16];
#pragma unroll
  for (int s = 0; s < 16; s++) wv[s] = W[src[s]]; // all 16 in flight
#pragma unroll
  for (int m = 0; m < 4; m++) {
    vf4 v = lds4[t + THREADS * m];
#pragma unroll
    for (int c = 0; c < 4; c++) v[c] *= wv[4 * m + c];
    lds4[t + THREADS * m] = v;
  }
  __syncthreads();
  fwht_lo_rounds<true>(lds, t, (vf4*)out + base4);
}

// P4: FWHT bits 14..23 fused, full-line global accesses.
// j = s*2^22 + r*2^14 + c  (s=segment bits 22..23, r=row bits 14..21, c low).
// Block owns cols [c0, c0+32) (= 128B) for ALL r and ALL s.
//  step 1: per thread load its (r,c) vf4 from all 4 segments -> regs,
//          radix-4 over s in registers (bits 22..23).
//  step 2: for each segment: stage its 256x32-float tile in 32KB LDS,
//          4 radix-4 LDS rounds (bits 14..21), last round streams to global.
// 512 threads, 512 blocks. lds4 idx = row*8+c4 -> bank-quad = c4 (uniform,
// conflict-free in every round; no swizzle needed).
__global__ __launch_bounds__(K4_THREADS, 4) void k4_fwht_hi(
    float* __restrict__ out) {
  __shared__ vf4 lds4[2048]; // 256 rows x 8 vf4-cols = 32KB
  const int t = threadIdx.x;
  const unsigned c04 = (unsigned)blockIdx.x * 8u; // vf4-col base (of 4096)
  vf4* O4 = (vf4*)out;

  vf4 a[4][4]; // [segment][m] — all indices compile-time via unroll
#pragma unroll
  for (int s = 0; s < 4; s++) {
#pragma unroll
    for (int m = 0; m < 4; m++) {
      const int idx4 = t + K4_THREADS * m;
      const int row = idx4 >> 3, c4 = idx4 & 7;
      a[s][m] =
          O4[((unsigned)s << 20) + (unsigned)row * 4096u + c04 + (unsigned)c4];
    }
  }
  // bits 22..23: radix-4 across segments, in registers
#pragma unroll
  for (int m = 0; m < 4; m++) {
    vf4 e0 = a[0][m] + a[1][m], e1 = a[0][m] - a[1][m];
    vf4 e2 = a[2][m] + a[3][m], e3 = a[2][m] - a[3][m];
    a[0][m] = e0 + e2;
    a[1][m] = e1 + e3;
    a[2][m] = e0 - e2;
    a[3][m] = e1 - e3;
  }
  const int c4 = t & 7;
  const int f = t >> 3; // 0..63
#pragma unroll
  for (int s = 0; s < 4; s++) {
    if (s) __syncthreads(); // previous segment's LDS reads done
#pragma unroll
    for (int m = 0; m < 4; m++) lds4[t + K4_THREADS * m] = a[s][m];
    __syncthreads();
#pragma unroll
    for (int r = 0; r < 4; r++) {
      const int mm = 1 << (2 * r);
      int rows[4];
#pragma unroll
      for (int k = 0; k < 4; k++)
        rows[k] = (f & (mm - 1)) + k * mm + (f >> (2 * r)) * (mm << 2);
      vf4 v0 = lds4[rows[0] * 8 + c4];
      vf4 v1 = lds4[rows[1] * 8 + c4];
      vf4 v2 = lds4[rows[2] * 8 + c4];
      vf4 v3 = lds4[rows[3] * 8 + c4];
      vf4 e0 = v0 + v1, e1 = v0 - v1;
      vf4 e2 = v2 + v3, e3 = v2 - v3;
      vf4 o0 = e0 + e2, o1 = e1 + e3, o2 = e0 - e2, o3 = e1 - e3;
      if (r < 3) {
        lds4[rows[0] * 8 + c4] = o0;
        lds4[rows[1] * 8 + c4] = o1;
        lds4[rows[2] * 8 + c4] = o2;
        lds4[rows[3] * 8 + c4] = o3;
        __syncthreads();
      } else {
        const unsigned sb = ((unsigned)s << 20) + c04 + (unsigned)c4;
        __builtin_nontemporal_store(o0, &O4[sb + (unsigned)rows[0] * 4096u]);
        __builtin_nontemporal_store(o1, &O4[sb + (unsigned)rows[1] * 4096u]);
        __builtin_nontemporal_store(o2, &O4[sb + (unsigned)rows[2] * 4096u]);
        __builtin_nontemporal_store(o3, &O4[sb + (unsigned)rows[3] * 4096u]);
      }
    }
  }
}

extern "C" void kernel_launch(void* const* d_in, const int* in_sizes, int n_in,
                              void* d_out, int out_size, void* d_ws,
                              size_t ws_size, hipStream_t stream) {
  (void)in_sizes;
  (void)n_in;
  (void)out_size;
  (void)ws_size;
  const float* A = (const float*)d_in[0];   // (16, 2048)
  const float* Bw = (const float*)d_in[1];  // (2048, 16)
  const float* G = (const float*)d_in[2];   // (2^24,)
  const float* sgn = (const float*)d_in[3]; // (2^24,)
  const int* perm = (const int*)d_in[4];    // (2^24,) int32
  float* out = (float*)d_out;               // (2^24,) f32
  float* W = (float*)d_ws;                  // 2^22 floats = 16MB scratch

  k1_build_fwht_lo<<<256, THREADS, 0, stream>>>(A, Bw, sgn, W);
  k_fwht_mid<<<256, THREADS, 0, stream>>>(W);              // P2 on ws
  k3_perm_fwht_lo<<<1024, THREADS, 0, stream>>>(W, perm, G, out);
  k4_fwht_hi<<<512, K4_THREADS, 0, stream>>>(out);         // P4 bits 14..23
}

// Round 5
// 349.489 us; speedup vs baseline: 1.3474x; 1.3474x over previous
//
#include <hip/hip_runtime.h>

// SuperLoRAGroup: out = FWHT24( G * Pi( FWHT24( pad( sign * vec(Bw@A)/16 ) ) ) )
// FWHT1 output periodic with period 2^22 => gather table W = 16MB only.
//
// P1 : GEMM+sign fused, FWHT bits 0..13 per 16K chunk            -> ws (16MB)
// P2 : FWHT bits 14..21 (256-pt, stride 2^14), in-place on ws    (k_fwht_mid)
// P3 : z[j] = ws[perm[j]&m]*G[j]*2^-24, FWHT bits 0..13          -> d_out
//      gathers phase-partitioned into 8x 2MB W-slices. MEASURED (r0-r4):
//      phased variants (4ph/drain, 4ph/vmcnt8, 8ph/vmcnt4) all 134-137us;
//      UNPHASED = 255us, FETCH 340->859MB (every gather misses L2, pulls a
//      full line). Phasing is required for L2 service; beyond that k3 sits
//      at a ~4 cyc/lane-address gather-rate floor (65K addrs/CU).
// P4 : FWHT bits 14..23 fused in ONE pass: bits 22..23 radix-4 in REGISTERS,
//      then bits 14..21 per segment through a 32KB LDS tile (256x32 floats).
//      All global accesses are full 128B lines per row.

#define THREADS 1024
#define K4_THREADS 512

typedef float vf4 __attribute__((ext_vector_type(4)));
typedef int vi4 __attribute__((ext_vector_type(4)));

constexpr float kScaling = 0.0625f;             // alpha/rank = 1/16
constexpr float kNorm = 5.9604644775390625e-8f; // 2^-24 (both fwht norms)

__device__ __forceinline__ void fwht16(float r[16]) {
#pragma unroll
  for (int s = 1; s < 16; s <<= 1) {
#pragma unroll
    for (int i = 0; i < 16; i++) {
      if (!(i & s)) {
        float a = r[i];
        float b = r[i | s];
        r[i] = a + b;
        r[i | s] = a - b;
      }
    }
  }
}

// FWHT over the 14 low bits of a 16384-float LDS tile (radix 16/16/16/4).
// Final round streams results straight to dst4. Caller syncs after fill.
template <bool NT>
__device__ __forceinline__ void fwht_lo_rounds(float* lds, int t, vf4* dst4) {
  vf4* lds4 = (vf4*)lds;
  // bits 0..3: 16 contiguous floats per thread
  {
    float r[16];
#pragma unroll
    for (int q = 0; q < 4; q++) {
      vf4 v = lds4[t * 4 + q];
#pragma unroll
      for (int c = 0; c < 4; c++) r[4 * q + c] = v[c];
    }
    fwht16(r);
#pragma unroll
    for (int q = 0; q < 4; q++) {
      vf4 v;
#pragma unroll
      for (int c = 0; c < 4; c++) v[c] = r[4 * q + c];
      lds4[t * 4 + q] = v;
    }
  }
  __syncthreads();
  // bits 4..7 (b32 stride 16)
  {
    const int c = (t & 15) | ((t >> 4) << 8);
    float r[16];
#pragma unroll
    for (int k = 0; k < 16; k++) r[k] = lds[c + (k << 4)];
    fwht16(r);
#pragma unroll
    for (int k = 0; k < 16; k++) lds[c + (k << 4)] = r[k];
  }
  __syncthreads();
  // bits 8..11 (b32 stride 256)
  {
    const int c = (t & 255) | ((t >> 8) << 12);
    float r[16];
#pragma unroll
    for (int k = 0; k < 16; k++) r[k] = lds[c + (k << 8)];
    fwht16(r);
#pragma unroll
    for (int k = 0; k < 16; k++) lds[c + (k << 8)] = r[k];
  }
  __syncthreads();
  // bits 12..13 (radix-4 on float4 payload) fused with global store
  {
    vf4 v0 = lds4[t + 0 * 1024];
    vf4 v1 = lds4[t + 1 * 1024];
    vf4 v2 = lds4[t + 2 * 1024];
    vf4 v3 = lds4[t + 3 * 1024];
    vf4 e0 = v0 + v1, e1 = v0 - v1;
    vf4 e2 = v2 + v3, e3 = v2 - v3;
    vf4 o0 = e0 + e2, o1 = e1 + e3, o2 = e0 - e2, o3 = e1 - e3;
    if (NT) {
      __builtin_nontemporal_store(o0, &dst4[t + 0 * 1024]);
      __builtin_nontemporal_store(o1, &dst4[t + 1 * 1024]);
      __builtin_nontemporal_store(o2, &dst4[t + 2 * 1024]);
      __builtin_nontemporal_store(o3, &dst4[t + 3 * 1024]);
    } else {
      dst4[t + 0 * 1024] = o0;
      dst4[t + 1 * 1024] = o1;
      dst4[t + 2 * 1024] = o2;
      dst4[t + 3 * 1024] = o3;
    }
  }
}

// P1: delta=(Bw@A)/16, *sign, FWHT bits0..13 -> W. 256 blocks.
// sgn is streamed nontemporally (single use; keep L2 for A/W).
__global__ __launch_bounds__(THREADS) void k1_build_fwht_lo(
    const float* __restrict__ A, const float* __restrict__ Bw,
    const float* __restrict__ sgn, float* __restrict__ W) {
  __shared__ float lds[16384];
  const int t = threadIdx.x;
  const int blk = blockIdx.x;
  const unsigned base = (unsigned)blk << 14;

  float a0[16], a1[16];
#pragma unroll
  for (int k = 0; k < 16; k++) {
    a0[k] = A[k * 2048 + t];
    a1[k] = A[k * 2048 + t + 1024];
  }
  const int r0 = blk * 8;
#pragma unroll
  for (int rl = 0; rl < 8; rl++) {
    float s0 = 0.f, s1 = 0.f;
#pragma unroll
    for (int k = 0; k < 16; k++) {
      float b = Bw[(r0 + rl) * 16 + k];
      s0 += b * a0[k];
      s1 += b * a1[k];
    }
    const int l0 = rl * 2048 + t;
    const int l1 = l0 + 1024;
    lds[l0] = s0 * kScaling * __builtin_nontemporal_load(&sgn[base + l0]);
    lds[l1] = s1 * kScaling * __builtin_nontemporal_load(&sgn[base + l1]);
  }
  __syncthreads();
  fwht_lo_rounds<false>(lds, t, (vf4*)W + ((unsigned)blk << 12));
}

// 256-pt FWHT over bits 14..21 within a 2^22-float segment, in-place.
// Grid = n_segments*256; seg = blockIdx>>8, col-tile = blockIdx&255.
// (Used for the W workspace only.)
__global__ __launch_bounds__(THREADS) void k_fwht_mid(float* __restrict__ buf) {
  __shared__ float lds[16384];
  vf4* lds4 = (vf4*)lds;
  const int t = threadIdx.x;
  const int seg = blockIdx.x >> 8;
  const int c0 = (blockIdx.x & 255) * 16; // float4-column base
  vf4* B4 = (vf4*)buf + ((unsigned)seg << 20); // 256 rows x 4096 f4-cols
#pragma unroll
  for (int m = 0; m < 4; m++) {
    const int idx4 = t + THREADS * m;
    const int row = idx4 >> 4, c4 = idx4 & 15;
    lds4[idx4] = B4[row * 4096 + c0 + c4]; // 256B/row segments
  }
  __syncthreads();
  const int c4 = t & 15;
  const int f = t >> 4; // 0..63
#pragma unroll
  for (int r = 0; r < 4; r++) {
    const int m = 1 << (2 * r);
    int rows[4];
#pragma unroll
    for (int k2 = 0; k2 < 4; k2++)
      rows[k2] = (f & (m - 1)) + k2 * m + (f >> (2 * r)) * (m << 2);
    vf4 v0 = lds4[rows[0] * 16 + c4];
    vf4 v1 = lds4[rows[1] * 16 + c4];
    vf4 v2 = lds4[rows[2] * 16 + c4];
    vf4 v3 = lds4[rows[3] * 16 + c4];
    vf4 e0 = v0 + v1, e1 = v0 - v1;
    vf4 e2 = v2 + v3, e3 = v2 - v3;
    vf4 o0 = e0 + e2, o1 = e1 + e3, o2 = e0 - e2, o3 = e1 - e3;
    if (r < 3) {
      lds4[rows[0] * 16 + c4] = o0;
      lds4[rows[1] * 16 + c4] = o1;
      lds4[rows[2] * 16 + c4] = o2;
      lds4[rows[3] * 16 + c4] = o3;
      __syncthreads();
    } else {
      B4[rows[0] * 4096 + c0 + c4] = o0;
      B4[rows[1] * 4096 + c0 + c4] = o1;
      B4[rows[2] * 4096 + c0 + c4] = o2;
      B4[rows[3] * 4096 + c0 + c4] = o3;
    }
  }
}

// P3: z = W[perm&mask]*G*2^-24, FWHT bits0..13 -> out. 1024 blocks.
// 8 gather phases of 2MB each keep the active W-slice L2-resident (half the
// 4MB/XCD L2 free for stream transients). vmcnt(4) + raw s_barrier pacing
// keeps ~1 phase of lookahead in flight. Unphased variant measured +121us
// (every gather misses L2). G*2^-24 pre-staged in LDS keeps VGPRs <= 64
// (2 blocks/CU at 64KB LDS needs 8 waves/SIMD).
__global__ __launch_bounds__(THREADS, 8) void k3_perm_fwht_lo(
    const float* __restrict__ W, const int* __restrict__ perm,
    const float* __restrict__ G, float* __restrict__ out) {
  __shared__ float lds[16384];
  vf4* lds4 = (vf4*)lds;
  const int t = threadIdx.x;
  const unsigned base4 = (unsigned)blockIdx.x << 12;
  const vi4* P4 = (const vi4*)perm + base4;
  const vf4* G4 = (const vf4*)G + base4;
  int src[16];
#pragma unroll
  for (int m = 0; m < 4; m++) {
    const int idx4 = t + THREADS * m;
    vi4 p = __builtin_nontemporal_load(&P4[idx4]);
    vf4 g = __builtin_nontemporal_load(&G4[idx4]);
#pragma unroll
    for (int c = 0; c < 4; c++) src[4 * m + c] = p[c] & 0x3FFFFF;
    lds4[idx4] = g * kNorm; // own slot; no cross-thread use until final sync
  }
  float wv[16];
#pragma unroll
  for (int pass = 0; pass < 8; pass++) {
#pragma unroll
    for (int s = 0; s < 16; s++) {
      if ((src[s] >> 19) == pass) wv[s] = W[src[s]];
    }
    if (pass < 7) {
      // ~1 phase (avg 2 gathers/thread) of lookahead stays in flight
      asm volatile("s_waitcnt vmcnt(4)" ::: "memory");
      __builtin_amdgcn_s_barrier();
    }
  }
#pragma unroll
  for (int m = 0; m < 4; m++) {
    vf4 v = lds4[t + THREADS * m];
#pragma unroll
    for (int c = 0; c < 4; c++) v[c] *= wv[4 * m + c];
    lds4[t + THREADS * m] = v;
  }
  __syncthreads();
  fwht_lo_rounds<true>(lds, t, (vf4*)out + base4);
}

// P4: FWHT bits 14..23 fused, full-line global accesses.
// j = s*2^22 + r*2^14 + c  (s=segment bits 22..23, r=row bits 14..21, c low).
// Block owns cols [c0, c0+32) (= 128B) for ALL r and ALL s.
//  step 1: per thread load its (r,c) vf4 from all 4 segments -> regs,
//          radix-4 over s in registers (bits 22..23).
//  step 2: for each segment: stage its 256x32-float tile in 32KB LDS,
//          4 radix-4 LDS rounds (bits 14..21), last round streams to global.
// 512 threads, 512 blocks. lds4 idx = row*8+c4 -> bank-quad = c4 (uniform,
// conflict-free in every round; no swizzle needed).
__global__ __launch_bounds__(K4_THREADS, 4) void k4_fwht_hi(
    float* __restrict__ out) {
  __shared__ vf4 lds4[2048]; // 256 rows x 8 vf4-cols = 32KB
  const int t = threadIdx.x;
  const unsigned c04 = (unsigned)blockIdx.x * 8u; // vf4-col base (of 4096)
  vf4* O4 = (vf4*)out;

  vf4 a[4][4]; // [segment][m] — all indices compile-time via unroll
#pragma unroll
  for (int s = 0; s < 4; s++) {
#pragma unroll
    for (int m = 0; m < 4; m++) {
      const int idx4 = t + K4_THREADS * m;
      const int row = idx4 >> 3, c4 = idx4 & 7;
      a[s][m] =
          O4[((unsigned)s << 20) + (unsigned)row * 4096u + c04 + (unsigned)c4];
    }
  }
  // bits 22..23: radix-4 across segments, in registers
#pragma unroll
  for (int m = 0; m < 4; m++) {
    vf4 e0 = a[0][m] + a[1][m], e1 = a[0][m] - a[1][m];
    vf4 e2 = a[2][m] + a[3][m], e3 = a[2][m] - a[3][m];
    a[0][m] = e0 + e2;
    a[1][m] = e1 + e3;
    a[2][m] = e0 - e2;
    a[3][m] = e1 - e3;
  }
  const int c4 = t & 7;
  const int f = t >> 3; // 0..63
#pragma unroll
  for (int s = 0; s < 4; s++) {
    if (s) __syncthreads(); // previous segment's LDS reads done
#pragma unroll
    for (int m = 0; m < 4; m++) lds4[t + K4_THREADS * m] = a[s][m];
    __syncthreads();
#pragma unroll
    for (int r = 0; r < 4; r++) {
      const int mm = 1 << (2 * r);
      int rows[4];
#pragma unroll
      for (int k = 0; k < 4; k++)
        rows[k] = (f & (mm - 1)) + k * mm + (f >> (2 * r)) * (mm << 2);
      vf4 v0 = lds4[rows[0] * 8 + c4];
      vf4 v1 = lds4[rows[1] * 8 + c4];
      vf4 v2 = lds4[rows[2] * 8 + c4];
      vf4 v3 = lds4[rows[3] * 8 + c4];
      vf4 e0 = v0 + v1, e1 = v0 - v1;
      vf4 e2 = v2 + v3, e3 = v2 - v3;
      vf4 o0 = e0 + e2, o1 = e1 + e3, o2 = e0 - e2, o3 = e1 - e3;
      if (r < 3) {
        lds4[rows[0] * 8 + c4] = o0;
        lds4[rows[1] * 8 + c4] = o1;
        lds4[rows[2] * 8 + c4] = o2;
        lds4[rows[3] * 8 + c4] = o3;
        __syncthreads();
      } else {
        const unsigned sb = ((unsigned)s << 20) + c04 + (unsigned)c4;
        __builtin_nontemporal_store(o0, &O4[sb + (unsigned)rows[0] * 4096u]);
        __builtin_nontemporal_store(o1, &O4[sb + (unsigned)rows[1] * 4096u]);
        __builtin_nontemporal_store(o2, &O4[sb + (unsigned)rows[2] * 4096u]);
        __builtin_nontemporal_store(o3, &O4[sb + (unsigned)rows[3] * 4096u]);
      }
    }
  }
}

extern "C" void kernel_launch(void* const* d_in, const int* in_sizes, int n_in,
                              void* d_out, int out_size, void* d_ws,
                              size_t ws_size, hipStream_t stream) {
  (void)in_sizes;
  (void)n_in;
  (void)out_size;
  (void)ws_size;
  const float* A = (const float*)d_in[0];   // (16, 2048)
  const float* Bw = (const float*)d_in[1];  // (2048, 16)
  const float* G = (const float*)d_in[2];   // (2^24,)
  const float* sgn = (const float*)d_in[3]; // (2^24,)
  const int* perm = (const int*)d_in[4];    // (2^24,) int32
  float* out = (float*)d_out;               // (2^24,) f32
  float* W = (float*)d_ws;                  // 2^22 floats = 16MB scratch

  k1_build_fwht_lo<<<256, THREADS, 0, stream>>>(A, Bw, sgn, W);
  k_fwht_mid<<<256, THREADS, 0, stream>>>(W);              // P2 on ws
  k3_perm_fwht_lo<<<1024, THREADS, 0, stream>>>(W, perm, G, out);
  k4_fwht_hi<<<512, K4_THREADS, 0, stream>>>(out);         // P4 bits 14..23
}